// Round 1
// baseline (3175.632 us; speedup 1.0000x reference)
//
#include <hip/hip_runtime.h>
#include <hip/hip_bf16.h>

#define KAN_GRID 30
#define KAN_HID  16

// -------- Kernel 1: betas[n]*dt for all n (embarrassingly parallel) --------
__global__ __launch_bounds__(256) void kan_betas_kernel(
    const float* __restrict__ t,
    const float* __restrict__ sw1,   // [30,16]
    const float* __restrict__ bw1,   // [16,1]
    const float* __restrict__ sw2,   // [480,1]
    const float* __restrict__ bw2,   // [1,16]
    float* __restrict__ beta_dt,     // [T]
    int T)
{
    __shared__ float s_sw1[KAN_GRID * KAN_HID];
    __shared__ float s_sw2[KAN_HID * KAN_GRID];
    __shared__ float s_bw1[KAN_HID];
    __shared__ float s_bw2[KAN_HID];

    for (int i = threadIdx.x; i < KAN_GRID * KAN_HID; i += blockDim.x) {
        s_sw1[i] = sw1[i];
        s_sw2[i] = sw2[i];
    }
    if (threadIdx.x < KAN_HID) {
        s_bw1[threadIdx.x] = bw1[threadIdx.x];
        s_bw2[threadIdx.x] = bw2[threadIdx.x];
    }
    __syncthreads();

    int n = blockIdx.x * blockDim.x + threadIdx.x;
    if (n >= T) return;

    float tv = t[n];
    float dt = t[1] - t[0];

    // Layer 1: h[j] = t*bw1[j] + sum_g exp(-20*(t-g/29)^2) * sw1[g][j]
    float h[KAN_HID];
#pragma unroll
    for (int j = 0; j < KAN_HID; ++j) h[j] = tv * s_bw1[j];

#pragma unroll
    for (int g = 0; g < KAN_GRID; ++g) {
        float d = tv - (float)g * (1.0f / 29.0f);
        float e = __expf(-20.0f * d * d);
#pragma unroll
        for (int j = 0; j < KAN_HID; ++j)
            h[j] = fmaf(e, s_sw1[g * KAN_HID + j], h[j]);
    }

    // Layer 2: out = sum_j h[j]*bw2[j] + sum_j sum_g exp(-20*(h[j]-g/29)^2)*sw2[j*30+g]
    float out = 0.0f;
#pragma unroll
    for (int j = 0; j < KAN_HID; ++j) out = fmaf(h[j], s_bw2[j], out);

#pragma unroll
    for (int j = 0; j < KAN_HID; ++j) {
        float hv = h[j];
#pragma unroll
        for (int g = 0; g < KAN_GRID; ++g) {
            float d = hv - (float)g * (1.0f / 29.0f);
            out = fmaf(__expf(-20.0f * d * d), s_sw2[j * KAN_GRID + g], out);
        }
    }

    // softplus (stable): max(x,0) + log1p(exp(-|x|))
    float beta = fmaxf(out, 0.0f) + log1pf(__expf(-fabsf(out)));
    beta_dt[n] = beta * dt;
}

// -------- Kernel 2: sequential SIR scan (single lane, latency-bound) --------
// One step. Dependent chain: x=S*I (4cy) -> fma (4cy) -> med3 clamp (4cy).
#define SIR_STEP(BDT, RES)                          \
    {                                               \
        float x  = S * I;                           \
        float q  = fmaf(-gdt, I, I);                \
        float Sn = fmaf(-(BDT), x, S);              \
        float In = fmaf((BDT), x, q);               \
        Sn = fminf(fmaxf(Sn, 0.0f), 1.0f);          \
        In = fminf(fmaxf(In, 0.0f), 1.0f);          \
        S = Sn; I = In; (RES) = In;                 \
    }

__global__ void kan_sir_scan_kernel(
    const float* __restrict__ t,
    const float* __restrict__ I_init,
    const float* __restrict__ gamma_param,
    const float* beta_dt,   // no restrict: may alias out (ws fallback)
    float* out,
    int T)
{
    if (threadIdx.x != 0 || blockIdx.x != 0) return;

    float dt = t[1] - t[0];
    float gp = gamma_param[0];
    float gamma = fmaxf(gp, 0.0f) + log1pf(__expf(-fabsf(gp)));
    float gdt = gamma * dt;

    float I = I_init[0];
    float S = 1.0f - I;

    const float4* b4 = (const float4*)beta_dt;
    float4* o4 = (float4*)out;
    int nvec = T >> 2;  // T = 100000, divisible by 4

    const int PF = 8;   // prefetch depth in float4 (32 steps ahead ~ 384 cyc)
    float4 buf[PF];
#pragma unroll
    for (int i = 0; i < PF; ++i)
        buf[i] = (i < nvec) ? b4[i] : float4{0.0f, 0.0f, 0.0f, 0.0f};

    for (int base = 0; base < nvec; base += PF) {
#pragma unroll
        for (int i = 0; i < PF; ++i) {      // static index -> registers
            int c = base + i;
            if (c >= nvec) break;
            float4 b = buf[i];
            int nxt = c + PF;
            if (nxt < nvec) buf[i] = b4[nxt];   // prefetch, 8 iters ahead

            float4 r;
            SIR_STEP(b.x, r.x);
            SIR_STEP(b.y, r.y);
            SIR_STEP(b.z, r.z);
            SIR_STEP(b.w, r.w);
            o4[c] = r;
        }
    }

    // tail (T not divisible by 4) — not hit for T=100000
    for (int n = nvec << 2; n < T; ++n) {
        float bdt = beta_dt[n];
        float r;
        SIR_STEP(bdt, r);
        out[n] = r;
    }
}

extern "C" void kernel_launch(void* const* d_in, const int* in_sizes, int n_in,
                              void* d_out, int out_size, void* d_ws, size_t ws_size,
                              hipStream_t stream) {
    const float* t      = (const float*)d_in[0];
    const float* I_init = (const float*)d_in[1];
    const float* sw1    = (const float*)d_in[2];
    const float* bw1    = (const float*)d_in[3];
    const float* sw2    = (const float*)d_in[4];
    const float* bw2    = (const float*)d_in[5];
    const float* gp     = (const float*)d_in[6];
    int T = in_sizes[0];

    float* outf = (float*)d_out;
    // betas scratch: prefer d_ws; fall back to d_out (safe: in the scan,
    // reads of beta[c+8..] always precede the store to out[c], same thread).
    float* betab = (ws_size >= (size_t)T * sizeof(float)) ? (float*)d_ws : outf;

    int blocks = (T + 255) / 256;
    kan_betas_kernel<<<blocks, 256, 0, stream>>>(t, sw1, bw1, sw2, bw2, betab, T);
    kan_sir_scan_kernel<<<1, 64, 0, stream>>>(t, I_init, gp, betab, outf, T);
}

// Round 2
// 222.836 us; speedup vs baseline: 14.2510x; 14.2510x over previous
//
#include <hip/hip_runtime.h>
#include <hip/hip_bf16.h>

#define KAN_GRID 30
#define KAN_HID  16

#define PCHUNKS 250   // K: parareal chunks (threads)
#define PNITER  3     // Newton-parareal sweeps
#define PRING   8     // beta prefetch ring depth (registers, static-indexed)

// -------- Kernel 1: betas[n]*dt (embarrassingly parallel) --------
// transpose=1: write beta_dt[(n%L)*K + (n/L)]  (layout [L][K], coalesced reads
// in the chunk phase: thread k at step s reads beta_t[s*K + k]).
__global__ __launch_bounds__(256) void kan_betas_kernel(
    const float* __restrict__ t,
    const float* __restrict__ sw1,   // [30,16]
    const float* __restrict__ bw1,   // [16,1]
    const float* __restrict__ sw2,   // [480,1]
    const float* __restrict__ bw2,   // [1,16]
    float* __restrict__ beta_dt,
    int T, int K, int L, int transpose)
{
    __shared__ float s_sw1[KAN_GRID * KAN_HID];
    __shared__ float s_sw2[KAN_HID * KAN_GRID];
    __shared__ float s_bw1[KAN_HID];
    __shared__ float s_bw2[KAN_HID];

    for (int i = threadIdx.x; i < KAN_GRID * KAN_HID; i += blockDim.x) {
        s_sw1[i] = sw1[i];
        s_sw2[i] = sw2[i];
    }
    if (threadIdx.x < KAN_HID) {
        s_bw1[threadIdx.x] = bw1[threadIdx.x];
        s_bw2[threadIdx.x] = bw2[threadIdx.x];
    }
    __syncthreads();

    int n = blockIdx.x * blockDim.x + threadIdx.x;
    if (n >= T) return;

    float tv = t[n];
    float dt = t[1] - t[0];

    float h[KAN_HID];
#pragma unroll
    for (int j = 0; j < KAN_HID; ++j) h[j] = tv * s_bw1[j];

#pragma unroll
    for (int g = 0; g < KAN_GRID; ++g) {
        float d = tv - (float)g * (1.0f / 29.0f);
        float e = __expf(-20.0f * d * d);
#pragma unroll
        for (int j = 0; j < KAN_HID; ++j)
            h[j] = fmaf(e, s_sw1[g * KAN_HID + j], h[j]);
    }

    float out = 0.0f;
#pragma unroll
    for (int j = 0; j < KAN_HID; ++j) out = fmaf(h[j], s_bw2[j], out);

#pragma unroll
    for (int j = 0; j < KAN_HID; ++j) {
        float hv = h[j];
#pragma unroll
        for (int g = 0; g < KAN_GRID; ++g) {
            float d = hv - (float)g * (1.0f / 29.0f);
            out = fmaf(__expf(-20.0f * d * d), s_sw2[j * KAN_GRID + g], out);
        }
    }

    float beta = fmaxf(out, 0.0f) + log1pf(__expf(-fabsf(out)));
    float val = beta * dt;

    int oi = transpose ? ((n % L) * K + (n / L)) : n;
    beta_dt[oi] = val;
}

// -------- shared step macros (identical arithmetic to round-1 validated) ----
#define STEP_O(BDT, DST)                            \
    {                                               \
        float x  = S * I;                           \
        float q  = fmaf(-gdt, I, I);                \
        float Sn = fmaf(-(BDT), x, S);              \
        float In = fmaf((BDT), x, q);               \
        Sn = fminf(fmaxf(Sn, 0.0f), 1.0f);          \
        In = fminf(fmaxf(In, 0.0f), 1.0f);          \
        S = Sn; I = In; (DST) = In;                 \
    }

// state step + 2x2 Jacobian propagation (clip derivative ignored: inactive)
#define STEP_J(BDT)                                          \
    {                                                        \
        float x  = S * I;                                    \
        float u  = (BDT) * I;                                \
        float v  = (BDT) * S;                                \
        float q  = fmaf(-gdt, I, I);                         \
        float Sn = fmaf(-(BDT), x, S);                       \
        float In = fmaf((BDT), x, q);                        \
        Sn = fminf(fmaxf(Sn, 0.0f), 1.0f);                   \
        In = fminf(fmaxf(In, 0.0f), 1.0f);                   \
        float w  = g1 + v;                                   \
        float a2 = fmaf(-v, jc, fmaf(-u, ja, ja));           \
        float b2 = fmaf(-v, jd, fmaf(-u, jb, jb));           \
        float c2 = fmaf(w, jc, u * ja);                      \
        float d2 = fmaf(w, jd, u * jb);                      \
        S = Sn; I = In; ja = a2; jb = b2; jc = c2; jd = d2;  \
    }

// -------- Kernel 2 (fast path): Newton-parareal, single block --------------
__global__ __launch_bounds__(256) void sir_parareal_kernel(
    const float* __restrict__ t,
    const float* __restrict__ I_init,
    const float* __restrict__ gamma_param,
    const float* __restrict__ beta_t,   // [L][K] transposed
    float* __restrict__ out,
    int T, int K, int L)
{
    __shared__ float gSs[PCHUNKS], gIs[PCHUNKS];
    __shared__ float GSs[PCHUNKS], GIs[PCHUNKS];
    __shared__ float Jas[PCHUNKS], Jbs[PCHUNKS], Jcs[PCHUNKS], Jds[PCHUNKS];

    int k = threadIdx.x;
    bool active = (k < K);

    float dt = t[1] - t[0];
    float gp = gamma_param[0];
    float gamma = fmaxf(gp, 0.0f) + log1pf(__expf(-fabsf(gp)));
    float gdt = gamma * dt;
    float g1 = 1.0f - gdt;

    float I0 = I_init[0];
    float S0 = 1.0f - I0;

    if (active) { gSs[k] = S0; gIs[k] = I0; }
    __syncthreads();

    int ngrp = L / PRING;

    for (int it = 0; it < PNITER; ++it) {
        if (active) {
            float S = gSs[k], I = gIs[k];
            float ja = 1.0f, jb = 0.0f, jc = 0.0f, jd = 1.0f;
            const float* bp = beta_t + k;
            float ring[PRING];
#pragma unroll
            for (int i = 0; i < PRING; ++i) ring[i] = bp[i * K];
            const float* pf = bp + PRING * K;

            for (int g = 0; g + 1 < ngrp; ++g) {
#pragma unroll
                for (int i = 0; i < PRING; ++i) {
                    float bdt = ring[i];
                    ring[i] = pf[i * K];     // prefetch 8 steps ahead
                    STEP_J(bdt);
                }
                pf += PRING * K;
            }
#pragma unroll
            for (int i = 0; i < PRING; ++i) {   // last group, no prefetch
                float bdt = ring[i];
                STEP_J(bdt);
            }

            GSs[k] = S; GIs[k] = I;
            Jas[k] = ja; Jbs[k] = jb; Jcs[k] = jc; Jds[k] = jd;
        }
        __syncthreads();

        if (threadIdx.x == 0) {
            // sequential affine sweep: s_{k+1} = G_k + J_k (s_k - g_k)
            float sS = S0, sI = I0;
            for (int kk = 0; kk < K; ++kk) {
                float oS = gSs[kk], oI = gIs[kk];
                gSs[kk] = sS; gIs[kk] = sI;
                float dS = sS - oS, dI = sI - oI;
                float nS = GSs[kk] + fmaf(Jas[kk], dS, Jbs[kk] * dI);
                float nI = GIs[kk] + fmaf(Jcs[kk], dS, Jds[kk] * dI);
                sS = nS; sI = nI;
            }
        }
        __syncthreads();
    }

    // final output pass from converged chunk starts (exact round-1 step math)
    if (active) {
        float S = gSs[k], I = gIs[k];
        const float* bp = beta_t + k;
        float* op = out + (size_t)k * L;
        float ring[PRING];
#pragma unroll
        for (int i = 0; i < PRING; ++i) ring[i] = bp[i * K];
        const float* pf = bp + PRING * K;

        int s = 0;
        for (int g = 0; g + 1 < ngrp; ++g) {
#pragma unroll
            for (int i = 0; i < PRING; ++i) {
                float bdt = ring[i];
                ring[i] = pf[i * K];
                float r;
                STEP_O(bdt, r);
                op[s + i] = r;
            }
            pf += PRING * K;
            s += PRING;
        }
#pragma unroll
        for (int i = 0; i < PRING; ++i) {
            float bdt = ring[i];
            float r;
            STEP_O(bdt, r);
            op[s + i] = r;
        }
    }
}

// -------- Fallback: round-1 serial scan (used if ws too small / odd T) -----
__global__ void kan_sir_scan_kernel(
    const float* __restrict__ t,
    const float* __restrict__ I_init,
    const float* __restrict__ gamma_param,
    const float* beta_dt,   // may alias out
    float* out,
    int T)
{
    if (threadIdx.x != 0 || blockIdx.x != 0) return;

    float dt = t[1] - t[0];
    float gp = gamma_param[0];
    float gamma = fmaxf(gp, 0.0f) + log1pf(__expf(-fabsf(gp)));
    float gdt = gamma * dt;

    float I = I_init[0];
    float S = 1.0f - I;

    const float4* b4 = (const float4*)beta_dt;
    float4* o4 = (float4*)out;
    int nvec = T >> 2;

    const int PF = 8;
    float4 buf[PF];
#pragma unroll
    for (int i = 0; i < PF; ++i)
        buf[i] = (i < nvec) ? b4[i] : float4{0.0f, 0.0f, 0.0f, 0.0f};

    for (int base = 0; base < nvec; base += PF) {
#pragma unroll
        for (int i = 0; i < PF; ++i) {
            int c = base + i;
            if (c >= nvec) break;
            float4 b = buf[i];
            int nxt = c + PF;
            if (nxt < nvec) buf[i] = b4[nxt];

            float4 r;
            STEP_O(b.x, r.x);
            STEP_O(b.y, r.y);
            STEP_O(b.z, r.z);
            STEP_O(b.w, r.w);
            o4[c] = r;
        }
    }
    for (int n = nvec << 2; n < T; ++n) {
        float bdt = beta_dt[n];
        float r;
        STEP_O(bdt, r);
        out[n] = r;
    }
}

extern "C" void kernel_launch(void* const* d_in, const int* in_sizes, int n_in,
                              void* d_out, int out_size, void* d_ws, size_t ws_size,
                              hipStream_t stream) {
    const float* t      = (const float*)d_in[0];
    const float* I_init = (const float*)d_in[1];
    const float* sw1    = (const float*)d_in[2];
    const float* bw1    = (const float*)d_in[3];
    const float* sw2    = (const float*)d_in[4];
    const float* bw2    = (const float*)d_in[5];
    const float* gp     = (const float*)d_in[6];
    int T = in_sizes[0];

    float* outf = (float*)d_out;
    int blocks = (T + 255) / 256;

    const int K = PCHUNKS;
    int L = T / K;
    bool fast = (T % K == 0) && (L % PRING == 0) && (L >= PRING) &&
                (ws_size >= (size_t)T * sizeof(float));

    if (fast) {
        float* beta_t = (float*)d_ws;
        kan_betas_kernel<<<blocks, 256, 0, stream>>>(t, sw1, bw1, sw2, bw2,
                                                     beta_t, T, K, L, 1);
        sir_parareal_kernel<<<1, 256, 0, stream>>>(t, I_init, gp, beta_t,
                                                   outf, T, K, L);
    } else {
        float* betab = (ws_size >= (size_t)T * sizeof(float)) ? (float*)d_ws : outf;
        kan_betas_kernel<<<blocks, 256, 0, stream>>>(t, sw1, bw1, sw2, bw2,
                                                     betab, T, T, 1, 0);
        kan_sir_scan_kernel<<<1, 64, 0, stream>>>(t, I_init, gp, betab, outf, T);
    }
}

// Round 3
// 52.614 us; speedup vs baseline: 60.3572x; 4.2353x over previous
//
#include <hip/hip_runtime.h>
#include <hip/hip_bf16.h>

#define KAN_GRID 30
#define KAN_HID  16

#define PK      2500   // fast-path chunks
#define PL      40     // steps per chunk (PK*PL == T == 100000)
#define PNITER  3      // Newton-parareal sweeps
#define SCAN_NPT 3     // elements per thread in scan (1024*3 >= PK)

// ---------------- Kernel 1: betas[n]*dt ------------------------------------
// Thread m computes time index n = (m%K)*L + m/K and writes beta_t[m]
// (coalesced store; [L][K] layout so chunk kernels read coalesced too).
// With K=T, L=1 this degenerates to the identity mapping (fallback path).
__global__ __launch_bounds__(256) void kan_betas_kernel(
    const float* __restrict__ t,
    const float* __restrict__ sw1,   // [30,16]
    const float* __restrict__ bw1,   // [16,1]
    const float* __restrict__ sw2,   // [480,1]
    const float* __restrict__ bw2,   // [1,16]
    float* __restrict__ beta_dt,
    int T, int K, int L)
{
    __shared__ float s_sw1[KAN_GRID * KAN_HID];
    __shared__ float s_sw2[KAN_HID * KAN_GRID];
    __shared__ float s_bw1[KAN_HID];
    __shared__ float s_bw2[KAN_HID];

    for (int i = threadIdx.x; i < KAN_GRID * KAN_HID; i += blockDim.x) {
        s_sw1[i] = sw1[i];
        s_sw2[i] = sw2[i];
    }
    if (threadIdx.x < KAN_HID) {
        s_bw1[threadIdx.x] = bw1[threadIdx.x];
        s_bw2[threadIdx.x] = bw2[threadIdx.x];
    }
    __syncthreads();

    int m = blockIdx.x * blockDim.x + threadIdx.x;
    if (m >= T) return;

    int n = (m % K) * L + m / K;     // gather-read index (reads cache fine)

    float tv = t[n];
    float dt = t[1] - t[0];

    float h[KAN_HID];
#pragma unroll
    for (int j = 0; j < KAN_HID; ++j) h[j] = tv * s_bw1[j];

#pragma unroll
    for (int g = 0; g < KAN_GRID; ++g) {
        float d = tv - (float)g * (1.0f / 29.0f);
        float e = __expf(-20.0f * d * d);
#pragma unroll
        for (int j = 0; j < KAN_HID; ++j)
            h[j] = fmaf(e, s_sw1[g * KAN_HID + j], h[j]);
    }

    float out = 0.0f;
#pragma unroll
    for (int j = 0; j < KAN_HID; ++j) out = fmaf(h[j], s_bw2[j], out);

#pragma unroll
    for (int j = 0; j < KAN_HID; ++j) {
        float hv = h[j];
#pragma unroll
        for (int g = 0; g < KAN_GRID; ++g) {
            float d = hv - (float)g * (1.0f / 29.0f);
            out = fmaf(__expf(-20.0f * d * d), s_sw2[j * KAN_GRID + g], out);
        }
    }

    float beta = fmaxf(out, 0.0f) + log1pf(__expf(-fabsf(out)));
    beta_dt[m] = beta * dt;          // coalesced
}

// ---------------- step macros (round-1 validated arithmetic) ---------------
#define STEP_O(BDT, DST)                            \
    {                                               \
        float x  = S * I;                           \
        float q  = fmaf(-gdt, I, I);                \
        float Sn = fmaf(-(BDT), x, S);              \
        float In = fmaf((BDT), x, q);               \
        Sn = fminf(fmaxf(Sn, 0.0f), 1.0f);          \
        In = fminf(fmaxf(In, 0.0f), 1.0f);          \
        S = Sn; I = In; (DST) = In;                 \
    }

#define STEP_J(BDT)                                          \
    {                                                        \
        float x  = S * I;                                    \
        float u  = (BDT) * I;                                \
        float v  = (BDT) * S;                                \
        float q  = fmaf(-gdt, I, I);                         \
        float Sn = fmaf(-(BDT), x, S);                       \
        float In = fmaf((BDT), x, q);                        \
        Sn = fminf(fmaxf(Sn, 0.0f), 1.0f);                   \
        In = fminf(fmaxf(In, 0.0f), 1.0f);                   \
        float w  = g1 + v;                                   \
        float a2 = fmaf(-v, jc, fmaf(-u, ja, ja));           \
        float b2 = fmaf(-v, jd, fmaf(-u, jb, jb));           \
        float c2 = fmaf(w, jc, u * ja);                      \
        float d2 = fmaf(w, jd, u * jb);                      \
        S = Sn; I = In; ja = a2; jb = b2; jc = c2; jd = d2;  \
    }

#define SOFTPLUS(X) (fmaxf((X), 0.0f) + log1pf(__expf(-fabsf(X))))

// ---------------- chunk propagation (state + Jacobian) ---------------------
template<int L, bool FIRST>
__global__ __launch_bounds__(256) void sir_chunk_kernel(
    const float* __restrict__ t,
    const float* __restrict__ I_init,
    const float* __restrict__ gamma_param,
    const float* __restrict__ beta_t,   // [L][K]
    const float2* __restrict__ gs,      // chunk-start guesses
    float* __restrict__ o_ja, float* __restrict__ o_jb,
    float* __restrict__ o_jc, float* __restrict__ o_jd,
    float* __restrict__ o_cs, float* __restrict__ o_ci,
    int K)
{
    int k = blockIdx.x * blockDim.x + threadIdx.x;
    if (k >= K) return;

    float dt = t[1] - t[0];
    float gdt = SOFTPLUS(gamma_param[0]) * dt;
    float g1 = 1.0f - gdt;
    float I0 = I_init[0];
    float S0 = 1.0f - I0;

    float S, I;
    if (FIRST) { S = S0; I = I0; }
    else       { float2 g = gs[k]; S = g.x; I = g.y; }
    float gS = S, gI = I;

    float b[L];
#pragma unroll
    for (int s = 0; s < L; ++s) b[s] = beta_t[s * K + k];   // coalesced

    float ja = 1.0f, jb = 0.0f, jc = 0.0f, jd = 1.0f;
#pragma unroll
    for (int s = 0; s < L; ++s) { float bdt = b[s]; STEP_J(bdt); }

    o_ja[k] = ja; o_jb[k] = jb; o_jc[k] = jc; o_jd[k] = jd;
    // affine constant c = G - J*g  (map: s_next = J*s + c)
    o_cs[k] = S - fmaf(ja, gS, jb * gI);
    o_ci[k] = I - fmaf(jc, gS, jd * gI);
}

// ---------------- parallel affine-map scan → new chunk starts --------------
// map (a,b,c,d | s,i): x -> [[a,b],[c,d]] x + (s,i).  compose(L,E) = L after E.
#define COMPOSE(ra,rb,rc,rd,rs,ri, La,Lb,Lc,Ld,Ls,Li, Ea,Eb,Ec,Ed,Es,Ei)   \
    {                                                                      \
        ra = fmaf(La, Ea, Lb * Ec);                                        \
        rb = fmaf(La, Eb, Lb * Ed);                                        \
        rc = fmaf(Lc, Ea, Ld * Ec);                                        \
        rd = fmaf(Lc, Eb, Ld * Ed);                                        \
        rs = fmaf(La, Es, fmaf(Lb, Ei, Ls));                               \
        ri = fmaf(Lc, Es, fmaf(Ld, Ei, Li));                               \
    }

template<int NPT>
__global__ __launch_bounds__(1024) void sir_scan_kernel(
    const float* __restrict__ I_init,
    const float* __restrict__ o_ja, const float* __restrict__ o_jb,
    const float* __restrict__ o_jc, const float* __restrict__ o_jd,
    const float* __restrict__ o_cs, const float* __restrict__ o_ci,
    float2* __restrict__ gs,
    int K)
{
    __shared__ float wm[16][6];   // per-wave inclusive totals
    __shared__ float we[16][6];   // per-wave exclusive prefixes

    int tid  = threadIdx.x;
    int lane = tid & 63;
    int wid  = tid >> 6;

    float I0 = I_init[0];
    float S0 = 1.0f - I0;

    // load my elements, serial-compose left->right
    float ea[NPT], eb[NPT], ec[NPT], ed[NPT], es[NPT], ei[NPT];
    float ma = 1.0f, mb = 0.0f, mc = 0.0f, md = 1.0f, ms = 0.0f, mi = 0.0f;
#pragma unroll
    for (int i = 0; i < NPT; ++i) {
        int e = tid * NPT + i;
        if (e < K) {
            ea[i] = o_ja[e]; eb[i] = o_jb[e]; ec[i] = o_jc[e];
            ed[i] = o_jd[e]; es[i] = o_cs[e]; ei[i] = o_ci[e];
        } else {
            ea[i] = 1.0f; eb[i] = 0.0f; ec[i] = 0.0f;
            ed[i] = 1.0f; es[i] = 0.0f; ei[i] = 0.0f;
        }
        float na, nb, nc, nd, ns, ni;
        COMPOSE(na,nb,nc,nd,ns,ni, ea[i],eb[i],ec[i],ed[i],es[i],ei[i],
                                   ma,mb,mc,md,ms,mi);
        ma=na; mb=nb; mc=nc; md=nd; ms=ns; mi=ni;
    }

    // 64-wide inclusive shfl scan
    for (int off = 1; off < 64; off <<= 1) {
        float pa = __shfl_up(ma, off), pb = __shfl_up(mb, off);
        float pc = __shfl_up(mc, off), pd = __shfl_up(md, off);
        float ps = __shfl_up(ms, off), pi = __shfl_up(mi, off);
        if (lane >= off) {
            float na, nb, nc, nd, ns, ni;
            COMPOSE(na,nb,nc,nd,ns,ni, ma,mb,mc,md,ms,mi, pa,pb,pc,pd,ps,pi);
            ma=na; mb=nb; mc=nc; md=nd; ms=ns; mi=ni;
        }
    }

    if (lane == 63) {
        wm[wid][0]=ma; wm[wid][1]=mb; wm[wid][2]=mc;
        wm[wid][3]=md; wm[wid][4]=ms; wm[wid][5]=mi;
    }
    __syncthreads();

    if (tid == 0) {   // exclusive scan of 16 wave totals (serial, tiny)
        float ra=1.0f, rb=0.0f, rc=0.0f, rd=1.0f, rs=0.0f, ri=0.0f;
        for (int w = 0; w < 16; ++w) {
            we[w][0]=ra; we[w][1]=rb; we[w][2]=rc;
            we[w][3]=rd; we[w][4]=rs; we[w][5]=ri;
            float na, nb, nc, nd, ns, ni;
            COMPOSE(na,nb,nc,nd,ns,ni,
                    wm[w][0],wm[w][1],wm[w][2],wm[w][3],wm[w][4],wm[w][5],
                    ra,rb,rc,rd,rs,ri);
            ra=na; rb=nb; rc=nc; rd=nd; rs=ns; ri=ni;
        }
    }
    __syncthreads();

    // thread-exclusive prefix X = (wave-exclusive lane prefix) ∘ we[wid]
    float xa = __shfl_up(ma, 1), xb = __shfl_up(mb, 1);
    float xc = __shfl_up(mc, 1), xd = __shfl_up(md, 1);
    float xs = __shfl_up(ms, 1), xi = __shfl_up(mi, 1);
    if (lane == 0) { xa=1.0f; xb=0.0f; xc=0.0f; xd=1.0f; xs=0.0f; xi=0.0f; }
    float Ea = we[wid][0], Eb = we[wid][1], Ec = we[wid][2];
    float Ed = we[wid][3], Es = we[wid][4], Ei = we[wid][5];
    float ca, cb, cc, cd, cs, ci;
    COMPOSE(ca,cb,cc,cd,cs,ci, xa,xb,xc,xd,xs,xi, Ea,Eb,Ec,Ed,Es,Ei);

    // walk my elements: inclusive per-element prefix; new start for chunk e+1
#pragma unroll
    for (int i = 0; i < NPT; ++i) {
        int e = tid * NPT + i;
        float na, nb, nc, nd, ns, ni;
        COMPOSE(na,nb,nc,nd,ns,ni, ea[i],eb[i],ec[i],ed[i],es[i],ei[i],
                                   ca,cb,cc,cd,cs,ci);
        ca=na; cb=nb; cc=nc; cd=nd; cs=ns; ci=ni;
        if (e < K && (e + 1) < K) {
            float nS = fmaf(ca, S0, fmaf(cb, I0, cs));
            float nI = fmaf(cc, S0, fmaf(cd, I0, ci));
            gs[e + 1] = make_float2(nS, nI);
        }
    }
    if (tid == 0) gs[0] = make_float2(S0, I0);
}

// ---------------- final output pass ----------------------------------------
template<int L>
__global__ __launch_bounds__(256) void sir_out_kernel(
    const float* __restrict__ t,
    const float* __restrict__ gamma_param,
    const float* __restrict__ beta_t,   // [L][K]
    const float2* __restrict__ gs,
    float* __restrict__ out,
    int K)
{
    int k = blockIdx.x * blockDim.x + threadIdx.x;
    if (k >= K) return;

    float dt = t[1] - t[0];
    float gdt = SOFTPLUS(gamma_param[0]) * dt;

    float2 g = gs[k];
    float S = g.x, I = g.y;

    float b[L];
#pragma unroll
    for (int s = 0; s < L; ++s) b[s] = beta_t[s * K + k];

    float r[L];
#pragma unroll
    for (int s = 0; s < L; ++s) { STEP_O(b[s], r[s]); }

    float4* o4 = (float4*)(out + (size_t)k * L);   // k*L*4 bytes, 16B aligned
#pragma unroll
    for (int i = 0; i < L / 4; ++i)
        o4[i] = make_float4(r[4*i], r[4*i+1], r[4*i+2], r[4*i+3]);
}

// ---------------- fallback: serial scan (round-1 validated) ----------------
__global__ void kan_sir_scan_kernel(
    const float* __restrict__ t,
    const float* __restrict__ I_init,
    const float* __restrict__ gamma_param,
    const float* beta_dt,   // may alias out
    float* out,
    int T)
{
    if (threadIdx.x != 0 || blockIdx.x != 0) return;

    float dt = t[1] - t[0];
    float gdt = SOFTPLUS(gamma_param[0]) * dt;

    float I = I_init[0];
    float S = 1.0f - I;

    const float4* b4 = (const float4*)beta_dt;
    float4* o4 = (float4*)out;
    int nvec = T >> 2;

    const int PF = 8;
    float4 buf[PF];
#pragma unroll
    for (int i = 0; i < PF; ++i)
        buf[i] = (i < nvec) ? b4[i] : float4{0.0f, 0.0f, 0.0f, 0.0f};

    for (int base = 0; base < nvec; base += PF) {
#pragma unroll
        for (int i = 0; i < PF; ++i) {
            int c = base + i;
            if (c >= nvec) break;
            float4 b = buf[i];
            int nxt = c + PF;
            if (nxt < nvec) buf[i] = b4[nxt];

            float4 r;
            STEP_O(b.x, r.x);
            STEP_O(b.y, r.y);
            STEP_O(b.z, r.z);
            STEP_O(b.w, r.w);
            o4[c] = r;
        }
    }
    for (int n = nvec << 2; n < T; ++n) {
        float bdt = beta_dt[n];
        float r;
        STEP_O(bdt, r);
        out[n] = r;
    }
}

extern "C" void kernel_launch(void* const* d_in, const int* in_sizes, int n_in,
                              void* d_out, int out_size, void* d_ws, size_t ws_size,
                              hipStream_t stream) {
    const float* t      = (const float*)d_in[0];
    const float* I_init = (const float*)d_in[1];
    const float* sw1    = (const float*)d_in[2];
    const float* bw1    = (const float*)d_in[3];
    const float* sw2    = (const float*)d_in[4];
    const float* bw2    = (const float*)d_in[5];
    const float* gp     = (const float*)d_in[6];
    int T = in_sizes[0];

    float* outf = (float*)d_out;
    float* ws   = (float*)d_ws;
    int bblocks = (T + 255) / 256;

    size_t need = ((size_t)T + 8 * PK) * sizeof(float);
    bool fast = (T == PK * PL) && (ws_size >= need);

    if (fast) {
        const int K = PK;
        float* beta_t = ws;                 // [L][K]
        float* o_ja = ws + T;
        float* o_jb = o_ja + K;
        float* o_jc = o_jb + K;
        float* o_jd = o_jc + K;
        float* o_cs = o_jd + K;
        float* o_ci = o_cs + K;
        float2* gs  = (float2*)(o_ci + K);  // offset (T+6K)*4 B, 8B-aligned

        kan_betas_kernel<<<bblocks, 256, 0, stream>>>(t, sw1, bw1, sw2, bw2,
                                                      beta_t, T, K, PL);
        int cblocks = (K + 255) / 256;
        for (int it = 0; it < PNITER; ++it) {
            if (it == 0)
                sir_chunk_kernel<PL, true><<<cblocks, 256, 0, stream>>>(
                    t, I_init, gp, beta_t, gs,
                    o_ja, o_jb, o_jc, o_jd, o_cs, o_ci, K);
            else
                sir_chunk_kernel<PL, false><<<cblocks, 256, 0, stream>>>(
                    t, I_init, gp, beta_t, gs,
                    o_ja, o_jb, o_jc, o_jd, o_cs, o_ci, K);
            sir_scan_kernel<SCAN_NPT><<<1, 1024, 0, stream>>>(
                I_init, o_ja, o_jb, o_jc, o_jd, o_cs, o_ci, gs, K);
        }
        sir_out_kernel<PL><<<cblocks, 256, 0, stream>>>(
            t, gp, beta_t, gs, outf, K);
    } else {
        float* betab = (ws_size >= (size_t)T * sizeof(float)) ? ws : outf;
        kan_betas_kernel<<<bblocks, 256, 0, stream>>>(t, sw1, bw1, sw2, bw2,
                                                      betab, T, T, 1);
        kan_sir_scan_kernel<<<1, 64, 0, stream>>>(t, I_init, gp, betab, outf, T);
    }
}

// Round 4
// 41.168 us; speedup vs baseline: 77.1375x; 1.2780x over previous
//
#include <hip/hip_runtime.h>
#include <hip/hip_bf16.h>

#define KAN_GRID 30
#define KAN_HID  16

#define PK   2500    // chunks
#define PL   40      // steps per chunk (PK*PL == T == 100000)
#define SNPT 10      // scan elements per thread (256*10 >= PK)

// ---------------- Kernel 1: betas[n]*dt ------------------------------------
// Thread m computes time index n = (m%K)*L + m/K and writes beta_t[m]
// (coalesced store; [L][K] layout so chunk kernels read coalesced).
__global__ __launch_bounds__(256) void kan_betas_kernel(
    const float* __restrict__ t,
    const float* __restrict__ sw1,   // [30,16]
    const float* __restrict__ bw1,   // [16,1]
    const float* __restrict__ sw2,   // [480,1]
    const float* __restrict__ bw2,   // [1,16]
    float* __restrict__ beta_dt,
    int T, int K, int L)
{
    __shared__ float s_sw1[KAN_GRID * KAN_HID];
    __shared__ float s_sw2[KAN_HID * KAN_GRID];
    __shared__ float s_bw1[KAN_HID];
    __shared__ float s_bw2[KAN_HID];

    for (int i = threadIdx.x; i < KAN_GRID * KAN_HID; i += blockDim.x) {
        s_sw1[i] = sw1[i];
        s_sw2[i] = sw2[i];
    }
    if (threadIdx.x < KAN_HID) {
        s_bw1[threadIdx.x] = bw1[threadIdx.x];
        s_bw2[threadIdx.x] = bw2[threadIdx.x];
    }
    __syncthreads();

    int m = blockIdx.x * blockDim.x + threadIdx.x;
    if (m >= T) return;

    int n = (m % K) * L + m / K;

    float tv = t[n];
    float dt = t[1] - t[0];

    float h[KAN_HID];
#pragma unroll
    for (int j = 0; j < KAN_HID; ++j) h[j] = tv * s_bw1[j];

#pragma unroll
    for (int g = 0; g < KAN_GRID; ++g) {
        float d = tv - (float)g * (1.0f / 29.0f);
        float e = __expf(-20.0f * d * d);
#pragma unroll
        for (int j = 0; j < KAN_HID; ++j)
            h[j] = fmaf(e, s_sw1[g * KAN_HID + j], h[j]);
    }

    float out = 0.0f;
#pragma unroll
    for (int j = 0; j < KAN_HID; ++j) out = fmaf(h[j], s_bw2[j], out);

#pragma unroll
    for (int j = 0; j < KAN_HID; ++j) {
        float hv = h[j];
#pragma unroll
        for (int g = 0; g < KAN_GRID; ++g) {
            float d = hv - (float)g * (1.0f / 29.0f);
            out = fmaf(__expf(-20.0f * d * d), s_sw2[j * KAN_GRID + g], out);
        }
    }

    float beta = fmaxf(out, 0.0f) + log1pf(__expf(-fabsf(out)));
    beta_dt[m] = beta * dt;
}

// ---------------- step macros (round-1 validated arithmetic) ---------------
#define STEP_O(BDT, DST)                            \
    {                                               \
        float x  = S * I;                           \
        float q  = fmaf(-gdt, I, I);                \
        float Sn = fmaf(-(BDT), x, S);              \
        float In = fmaf((BDT), x, q);               \
        Sn = fminf(fmaxf(Sn, 0.0f), 1.0f);          \
        In = fminf(fmaxf(In, 0.0f), 1.0f);          \
        S = Sn; I = In; (DST) = In;                 \
    }

#define STEP_J(BDT)                                          \
    {                                                        \
        float x  = S * I;                                    \
        float u  = (BDT) * I;                                \
        float v  = (BDT) * S;                                \
        float q  = fmaf(-gdt, I, I);                         \
        float Sn = fmaf(-(BDT), x, S);                       \
        float In = fmaf((BDT), x, q);                        \
        Sn = fminf(fmaxf(Sn, 0.0f), 1.0f);                   \
        In = fminf(fmaxf(In, 0.0f), 1.0f);                   \
        float w  = g1 + v;                                   \
        float a2 = fmaf(-v, jc, fmaf(-u, ja, ja));           \
        float b2 = fmaf(-v, jd, fmaf(-u, jb, jb));           \
        float c2 = fmaf(w, jc, u * ja);                      \
        float d2 = fmaf(w, jd, u * jb);                      \
        S = Sn; I = In; ja = a2; jb = b2; jc = c2; jd = d2;  \
    }

#define SOFTPLUS(X) (fmaxf((X), 0.0f) + log1pf(__expf(-fabsf(X))))

// affine map (a,b,c,d | s,i): x -> [[a,b],[c,d]] x + (s,i). compose = L after E.
#define COMPOSE(ra,rb,rc,rd,rs,ri, La,Lb,Lc,Ld,Ls,Li, Ea,Eb,Ec,Ed,Es,Ei)   \
    {                                                                      \
        ra = fmaf(La, Ea, Lb * Ec);                                        \
        rb = fmaf(La, Eb, Lb * Ed);                                        \
        rc = fmaf(Lc, Ea, Ld * Ec);                                        \
        rd = fmaf(Lc, Eb, Ld * Ed);                                        \
        rs = fmaf(La, Es, fmaf(Lb, Ei, Ls));                               \
        ri = fmaf(Lc, Es, fmaf(Ld, Ei, Li));                               \
    }

// ---------------- in-block redundant affine scan ---------------------------
// Every block computes chunk-start states g_e = (prefix of maps 0..e-1)(S0,I0)
// for ALL e<K into g_lds. All threads must enter (contains __syncthreads).
__device__ __forceinline__ void block_affine_scan(
    const float* __restrict__ ja, const float* __restrict__ jb,
    const float* __restrict__ jc, const float* __restrict__ jd,
    const float* __restrict__ cs, const float* __restrict__ ci,
    int K, float S0, float I0,
    float2* g_lds, float (*wm)[6], float (*we)[6])
{
    int tid  = threadIdx.x;
    int lane = tid & 63;
    int wid  = tid >> 6;

    float Fa[SNPT], Fb[SNPT], Fc[SNPT], Fd[SNPT], Fs[SNPT], Fi[SNPT];
    float ma = 1.0f, mb = 0.0f, mc = 0.0f, md = 1.0f, ms = 0.0f, mi = 0.0f;
#pragma unroll
    for (int i = 0; i < SNPT; ++i) {
        int e = tid * SNPT + i;
        if (e < K) {
            Fa[i] = ja[e]; Fb[i] = jb[e]; Fc[i] = jc[e];
            Fd[i] = jd[e]; Fs[i] = cs[e]; Fi[i] = ci[e];
        } else {
            Fa[i] = 1.0f; Fb[i] = 0.0f; Fc[i] = 0.0f;
            Fd[i] = 1.0f; Fs[i] = 0.0f; Fi[i] = 0.0f;
        }
        float na, nb, nc, nd, ns, ni;
        COMPOSE(na,nb,nc,nd,ns,ni, Fa[i],Fb[i],Fc[i],Fd[i],Fs[i],Fi[i],
                                   ma,mb,mc,md,ms,mi);
        ma=na; mb=nb; mc=nc; md=nd; ms=ns; mi=ni;
    }

    // 64-wide inclusive shfl scan
    for (int off = 1; off < 64; off <<= 1) {
        float pa = __shfl_up(ma, off), pb = __shfl_up(mb, off);
        float pc = __shfl_up(mc, off), pd = __shfl_up(md, off);
        float ps = __shfl_up(ms, off), pi = __shfl_up(mi, off);
        if (lane >= off) {
            float na, nb, nc, nd, ns, ni;
            COMPOSE(na,nb,nc,nd,ns,ni, ma,mb,mc,md,ms,mi, pa,pb,pc,pd,ps,pi);
            ma=na; mb=nb; mc=nc; md=nd; ms=ns; mi=ni;
        }
    }

    if (lane == 63) {
        wm[wid][0]=ma; wm[wid][1]=mb; wm[wid][2]=mc;
        wm[wid][3]=md; wm[wid][4]=ms; wm[wid][5]=mi;
    }
    __syncthreads();

    if (tid == 0) {   // exclusive scan of 4 wave totals
        float ra=1.0f, rb=0.0f, rc=0.0f, rd=1.0f, rs=0.0f, ri=0.0f;
        for (int w = 0; w < 4; ++w) {
            we[w][0]=ra; we[w][1]=rb; we[w][2]=rc;
            we[w][3]=rd; we[w][4]=rs; we[w][5]=ri;
            float na, nb, nc, nd, ns, ni;
            COMPOSE(na,nb,nc,nd,ns,ni,
                    wm[w][0],wm[w][1],wm[w][2],wm[w][3],wm[w][4],wm[w][5],
                    ra,rb,rc,rd,rs,ri);
            ra=na; rb=nb; rc=nc; rd=nd; rs=ns; ri=ni;
        }
    }
    __syncthreads();

    // thread-exclusive prefix C = (lane-exclusive) ∘ (wave-exclusive)
    float xa = __shfl_up(ma, 1), xb = __shfl_up(mb, 1);
    float xc = __shfl_up(mc, 1), xd = __shfl_up(md, 1);
    float xs = __shfl_up(ms, 1), xi = __shfl_up(mi, 1);
    if (lane == 0) { xa=1.0f; xb=0.0f; xc=0.0f; xd=1.0f; xs=0.0f; xi=0.0f; }
    float Ca, Cb, Cc, Cd, Cs, Ci;
    COMPOSE(Ca,Cb,Cc,Cd,Cs,Ci, xa,xb,xc,xd,xs,xi,
            we[wid][0],we[wid][1],we[wid][2],we[wid][3],we[wid][4],we[wid][5]);

    // walk: exclusive prefix before element e gives chunk-e start
#pragma unroll
    for (int i = 0; i < SNPT; ++i) {
        int e = tid * SNPT + i;
        if (e < K) {
            float gS = fmaf(Ca, S0, fmaf(Cb, I0, Cs));
            float gI = fmaf(Cc, S0, fmaf(Cd, I0, Ci));
            g_lds[e] = make_float2(gS, gI);
        }
        float na, nb, nc, nd, ns, ni;
        COMPOSE(na,nb,nc,nd,ns,ni, Fa[i],Fb[i],Fc[i],Fd[i],Fs[i],Fi[i],
                                   Ca,Cb,Cc,Cd,Cs,Ci);
        Ca=na; Cb=nb; Cc=nc; Cd=nd; Cs=ns; Ci=ni;
    }
    __syncthreads();
}

// ---------------- pass 1: chunks from uniform start (S0,I0) ----------------
template<int L>
__global__ __launch_bounds__(256) void sir_chunk_first_kernel(
    const float* __restrict__ t,
    const float* __restrict__ I_init,
    const float* __restrict__ gamma_param,
    const float* __restrict__ beta_t,   // [L][K]
    float* __restrict__ o_ja, float* __restrict__ o_jb,
    float* __restrict__ o_jc, float* __restrict__ o_jd,
    float* __restrict__ o_cs, float* __restrict__ o_ci,
    int K)
{
    int k = blockIdx.x * blockDim.x + threadIdx.x;
    if (k >= K) return;

    float dt = t[1] - t[0];
    float gdt = SOFTPLUS(gamma_param[0]) * dt;
    float g1 = 1.0f - gdt;
    float I0 = I_init[0];
    float S0 = 1.0f - I0;

    float S = S0, I = I0;

    float b[L];
#pragma unroll
    for (int s = 0; s < L; ++s) b[s] = beta_t[s * K + k];

    float ja = 1.0f, jb = 0.0f, jc = 0.0f, jd = 1.0f;
#pragma unroll
    for (int s = 0; s < L; ++s) { float bdt = b[s]; STEP_J(bdt); }

    o_ja[k] = ja; o_jb[k] = jb; o_jc[k] = jc; o_jd[k] = jd;
    o_cs[k] = S - fmaf(ja, S0, jb * I0);
    o_ci[k] = I - fmaf(jc, S0, jd * I0);
}

// ---------------- pass 2: in-block scan of setA, propagate, write setB -----
template<int L>
__global__ __launch_bounds__(256) void sir_chunk_scan_kernel(
    const float* __restrict__ t,
    const float* __restrict__ I_init,
    const float* __restrict__ gamma_param,
    const float* __restrict__ beta_t,
    const float* __restrict__ i_ja, const float* __restrict__ i_jb,
    const float* __restrict__ i_jc, const float* __restrict__ i_jd,
    const float* __restrict__ i_cs, const float* __restrict__ i_ci,
    float* __restrict__ o_ja, float* __restrict__ o_jb,
    float* __restrict__ o_jc, float* __restrict__ o_jd,
    float* __restrict__ o_cs, float* __restrict__ o_ci,
    int K)
{
    __shared__ float2 g_lds[PK];
    __shared__ float wm[4][6], we[4][6];

    float dt = t[1] - t[0];
    float gdt = SOFTPLUS(gamma_param[0]) * dt;
    float g1 = 1.0f - gdt;
    float I0 = I_init[0];
    float S0 = 1.0f - I0;

    block_affine_scan(i_ja, i_jb, i_jc, i_jd, i_cs, i_ci,
                      K, S0, I0, g_lds, wm, we);

    int k = blockIdx.x * blockDim.x + threadIdx.x;
    if (k >= K) return;

    float2 g = g_lds[k];
    float S = g.x, I = g.y;

    float b[L];
#pragma unroll
    for (int s = 0; s < L; ++s) b[s] = beta_t[s * K + k];

    float ja = 1.0f, jb = 0.0f, jc = 0.0f, jd = 1.0f;
#pragma unroll
    for (int s = 0; s < L; ++s) { float bdt = b[s]; STEP_J(bdt); }

    o_ja[k] = ja; o_jb[k] = jb; o_jc[k] = jc; o_jd[k] = jd;
    o_cs[k] = S - fmaf(ja, g.x, jb * g.y);
    o_ci[k] = I - fmaf(jc, g.x, jd * g.y);
}

// ---------------- pass 3: in-block scan of setB, output ---------------------
template<int L>
__global__ __launch_bounds__(256) void sir_out_scan_kernel(
    const float* __restrict__ t,
    const float* __restrict__ I_init,
    const float* __restrict__ gamma_param,
    const float* __restrict__ beta_t,
    const float* __restrict__ i_ja, const float* __restrict__ i_jb,
    const float* __restrict__ i_jc, const float* __restrict__ i_jd,
    const float* __restrict__ i_cs, const float* __restrict__ i_ci,
    float* __restrict__ out,
    int K)
{
    __shared__ float2 g_lds[PK];
    __shared__ float wm[4][6], we[4][6];

    float dt = t[1] - t[0];
    float gdt = SOFTPLUS(gamma_param[0]) * dt;
    float I0 = I_init[0];
    float S0 = 1.0f - I0;

    block_affine_scan(i_ja, i_jb, i_jc, i_jd, i_cs, i_ci,
                      K, S0, I0, g_lds, wm, we);

    int k = blockIdx.x * blockDim.x + threadIdx.x;
    if (k >= K) return;

    float2 g = g_lds[k];
    float S = g.x, I = g.y;

    float b[L];
#pragma unroll
    for (int s = 0; s < L; ++s) b[s] = beta_t[s * K + k];

    float r[L];
#pragma unroll
    for (int s = 0; s < L; ++s) { STEP_O(b[s], r[s]); }

    float4* o4 = (float4*)(out + (size_t)k * L);
#pragma unroll
    for (int i = 0; i < L / 4; ++i)
        o4[i] = make_float4(r[4*i], r[4*i+1], r[4*i+2], r[4*i+3]);
}

// ---------------- fallback: serial scan (round-1 validated) ----------------
__global__ void kan_sir_scan_kernel(
    const float* __restrict__ t,
    const float* __restrict__ I_init,
    const float* __restrict__ gamma_param,
    const float* beta_dt,   // may alias out
    float* out,
    int T)
{
    if (threadIdx.x != 0 || blockIdx.x != 0) return;

    float dt = t[1] - t[0];
    float gdt = SOFTPLUS(gamma_param[0]) * dt;

    float I = I_init[0];
    float S = 1.0f - I;

    const float4* b4 = (const float4*)beta_dt;
    float4* o4 = (float4*)out;
    int nvec = T >> 2;

    const int PF = 8;
    float4 buf[PF];
#pragma unroll
    for (int i = 0; i < PF; ++i)
        buf[i] = (i < nvec) ? b4[i] : float4{0.0f, 0.0f, 0.0f, 0.0f};

    for (int base = 0; base < nvec; base += PF) {
#pragma unroll
        for (int i = 0; i < PF; ++i) {
            int c = base + i;
            if (c >= nvec) break;
            float4 b = buf[i];
            int nxt = c + PF;
            if (nxt < nvec) buf[i] = b4[nxt];

            float4 r;
            STEP_O(b.x, r.x);
            STEP_O(b.y, r.y);
            STEP_O(b.z, r.z);
            STEP_O(b.w, r.w);
            o4[c] = r;
        }
    }
    for (int n = nvec << 2; n < T; ++n) {
        float bdt = beta_dt[n];
        float r;
        STEP_O(bdt, r);
        out[n] = r;
    }
}

extern "C" void kernel_launch(void* const* d_in, const int* in_sizes, int n_in,
                              void* d_out, int out_size, void* d_ws, size_t ws_size,
                              hipStream_t stream) {
    const float* t      = (const float*)d_in[0];
    const float* I_init = (const float*)d_in[1];
    const float* sw1    = (const float*)d_in[2];
    const float* bw1    = (const float*)d_in[3];
    const float* sw2    = (const float*)d_in[4];
    const float* bw2    = (const float*)d_in[5];
    const float* gp     = (const float*)d_in[6];
    int T = in_sizes[0];

    float* outf = (float*)d_out;
    float* ws   = (float*)d_ws;
    int bblocks = (T + 255) / 256;

    const int K = PK;
    size_t need = ((size_t)T + 12 * K) * sizeof(float);
    bool fast = (T == PK * PL) && (ws_size >= need);

    if (fast) {
        float* beta_t = ws;                 // [L][K]
        float* A = ws + T;                  // setA: 6K
        float* B = A + 6 * K;               // setB: 6K

        kan_betas_kernel<<<bblocks, 256, 0, stream>>>(t, sw1, bw1, sw2, bw2,
                                                      beta_t, T, K, PL);
        int cblocks = (K + 255) / 256;      // 10
        sir_chunk_first_kernel<PL><<<cblocks, 256, 0, stream>>>(
            t, I_init, gp, beta_t,
            A, A + K, A + 2*K, A + 3*K, A + 4*K, A + 5*K, K);
        sir_chunk_scan_kernel<PL><<<cblocks, 256, 0, stream>>>(
            t, I_init, gp, beta_t,
            A, A + K, A + 2*K, A + 3*K, A + 4*K, A + 5*K,
            B, B + K, B + 2*K, B + 3*K, B + 4*K, B + 5*K, K);
        sir_out_scan_kernel<PL><<<cblocks, 256, 0, stream>>>(
            t, I_init, gp, beta_t,
            B, B + K, B + 2*K, B + 3*K, B + 4*K, B + 5*K,
            outf, K);
    } else {
        float* betab = (ws_size >= (size_t)T * sizeof(float)) ? ws : outf;
        kan_betas_kernel<<<bblocks, 256, 0, stream>>>(t, sw1, bw1, sw2, bw2,
                                                      betab, T, T, 1);
        kan_sir_scan_kernel<<<1, 64, 0, stream>>>(t, I_init, gp, betab, outf, T);
    }
}